// Round 7
// baseline (186.290 us; speedup 1.0000x reference)
//
#include <hip/hip_runtime.h>
#include <hip/hip_bf16.h>
#include <math.h>

#define NPTS 2097152
#define IMGW 1024
#define IMGH 1024

typedef __attribute__((ext_vector_type(8))) short bf16x8;   // 8 bf16 = 4 VGPR
typedef __attribute__((ext_vector_type(4))) float f32x4;
typedef __attribute__((ext_vector_type(2))) float f32x2;
typedef __attribute__((ext_vector_type(4))) unsigned int u32x4;

// ws layout (bytes):
//   [0,      34816)  weight frags (17408 ushorts):
//       [0, 12288)     WB: fused [Wf(48xk) ; W0(10xk) ; bias row 58] -> K=64, N=192.
//                      12 ntiles x 2 ksteps x 64 lanes x 8 bf16 fragments.
//                      ntile 0..3 = gamma, 4..7 = beta, 8..11 = h0 cols.
//                      Row 58 holds bff/b0 (feature 58 == 1.0 in phase 1).
//       [12288,16384)  W1: 4 ntiles x 2 ksteps x 64 x 8
//       [16384,17408)  W2: 1 ntile  x 2 ksteps x 64 x 8  (cols 4..15 zero)
//   [34816, 100352)  tX: f32[1024][16]  = Wp_x @ spiral_x(px)          (64 KB)
//   [100352,165888)  tY: f32[1024][16]  = Wp_y @ spiral_y(py) + bp     (64 KB)
//   [165888,174080)  tS: float2[1024]   = {sin(2pi p/1024), sin(4pi p/1024)}
// Requires ws_size >= 174080 bytes.
#define TX_OFF 34816
#define TY_OFF 100352
#define TS_OFF 165888
#define PREP_ITEMS 51200   // 17408 + 16384 + 16384 + 1024

__device__ __forceinline__ unsigned short f2bf(float f) {
    __hip_bfloat16 h = __float2bfloat16(f);          // RTNE; pairs fuse to v_cvt_pk_bf16_f32
    return __builtin_bit_cast(unsigned short, h);
}
__device__ __forceinline__ unsigned pk2(float a, float b) {
    return (unsigned)f2bf(a) | ((unsigned)f2bf(b) << 16);
}
__device__ __forceinline__ f32x2 mk2(float a, float b) { f32x2 r; r.x = a; r.y = b; return r; }

__device__ __forceinline__ float s2pi(float r) { r = r - floorf(r); return __builtin_amdgcn_sinf(r); }
__device__ __forceinline__ float c2pi(float r) { r = r + 0.25f; r = r - floorf(r); return __builtin_amdgcn_sinf(r); }

__global__ __launch_bounds__(256) void prepack(
    const float* __restrict__ Wf, const float* __restrict__ W0,
    const float* __restrict__ W1, const float* __restrict__ W2,
    const float* __restrict__ Wp, const float* __restrict__ bp,
    const float* __restrict__ bff, const float* __restrict__ b0,
    unsigned short* __restrict__ ws)
{
    int idx = blockIdx.x * 256 + threadIdx.x;
    if (idx < 17408) {                           // ---- weight fragments ----
        float val = 0.f;
        if (idx < 12288) {                       // fused Wf|W0 -> B frags (K=64)
            int e = idx, i = e & 7, l = (e >> 3) & 63, ks = (e >> 9) & 1, n = e >> 10;
            int k = ks * 32 + (l >> 4) * 8 + i;
            int c16 = l & 15;
            if (n < 8) {
                if (k < 48) val = Wf[k * 128 + n * 16 + c16];
                else if (k == 58) val = bff[n * 16 + c16];           // bias row
            } else {
                if (k >= 48 && k < 58) val = W0[(k - 48) * 64 + (n - 8) * 16 + c16];
                else if (k == 58) val = b0[(n - 8) * 16 + c16];      // bias row
            }
        } else if (idx < 16384) {                // W1 (64x64)
            int e = idx - 12288, i = e & 7, l = (e >> 3) & 63, ks = (e >> 9) & 1, n = e >> 10;
            int k = ks * 32 + (l >> 4) * 8 + i;
            val = W1[k * 64 + n * 16 + (l & 15)];
        } else {                                 // W2 (64x4, N padded to 16)
            int e = idx - 16384, i = e & 7, l = (e >> 3) & 63, ks = (e >> 9) & 1;
            int k = ks * 32 + (l >> 4) * 8 + i;
            int c = l & 15;
            if (c < 4) val = W2[k * 4 + c];
        }
        ws[idx] = f2bf(val);
    } else if (idx < 33792) {                    // ---- tX ----
        int e = idx - 17408, p = e >> 4, j = e & 15;
        float xf = (float)p * (1.0f / IMGW);
        float s[6] = { s2pi(xf), c2pi(xf), s2pi(2.f * xf), c2pi(2.f * xf), s2pi(3.f * xf), c2pi(3.f * xf) };
        float a = 0.f;
        #pragma unroll
        for (int k = 0; k < 6; ++k) a = fmaf(s[k], Wp[k * 16 + j], a);
        ((float*)((char*)ws + TX_OFF))[p * 16 + j] = a;
    } else if (idx < 50176) {                    // ---- tY (bias folded) ----
        int e = idx - 33792, p = e >> 4, j = e & 15;
        float yf = (float)p * (1.0f / IMGH);
        float s[6] = { s2pi(yf), c2pi(yf), s2pi(2.f * yf), c2pi(2.f * yf), s2pi(3.f * yf), c2pi(3.f * yf) };
        float a = bp[j];
        #pragma unroll
        for (int k = 0; k < 6; ++k) a = fmaf(s[k], Wp[(6 + k) * 16 + j], a);
        ((float*)((char*)ws + TY_OFF))[p * 16 + j] = a;
    } else if (idx < 51200) {                    // ---- tS ----
        int p = idx - 50176;
        float xf = (float)p * (1.0f / IMGW);
        float2 v; v.x = s2pi(xf); v.y = s2pi(2.f * xf);
        ((float2*)((char*)ws + TS_OFF))[p] = v;
    }
}

// Exact-GELU (A&S 7.1.25 erf, |gelu err| < 1e-5) — R4's proven version.
__device__ __forceinline__ f32x2 gelu2(f32x2 x) {
    const f32x2 ax = __builtin_elementwise_abs(x);
    f32x2 den = __builtin_elementwise_fma(ax, mk2(0.33269077f, 0.33269077f), mk2(1.0f, 1.0f));
    f32x2 t; t.x = __builtin_amdgcn_rcpf(den.x); t.y = __builtin_amdgcn_rcpf(den.y);
    f32x2 p = __builtin_elementwise_fma(t, mk2(0.37392780f, 0.37392780f), mk2(-0.04793990f, -0.04793990f));
    p = __builtin_elementwise_fma(t, p, mk2(0.17401210f, 0.17401210f));
    p = p * t;
    f32x2 w = (ax * ax) * mk2(-0.72134752f, -0.72134752f);
    f32x2 e; e.x = __builtin_amdgcn_exp2f(w.x); e.y = __builtin_amdgcn_exp2f(w.y);
    f32x2 r = __builtin_elementwise_max(x, mk2(0.f, 0.f));
    return __builtin_elementwise_fma(-ax, p * e, r);
}

#define MFMA(a, b, c) __builtin_amdgcn_mfma_f32_16x16x32_bf16((a), (b), (c), 0, 0, 0)

// Compiler-only reorder fence. R7: all LDS traffic here is WAVE-PRIVATE and
// same-wave DS ops execute in program order (all 64 lanes execute each DS
// instruction together), so the previous hardware `s_waitcnt lgkmcnt(0)`
// drains (8 full stalls/wave) are replaced by zero-cost compiler barriers.
// The compiler still auto-inserts data-dependency lgkmcnt before any use of
// a ds_read result.
#define CFENCE() asm volatile("" ::: "memory")

// LDS: featL = 256 rows x 64 bf16 (128 B/row, XOR-swizzled 16B granules) = 32 KB.
// hT tiles alias the wave's own featL rows (dead after the A-fragment preload).
// Wave-private everywhere -> NO __syncthreads.
__global__ __launch_bounds__(256) void vfx_fwd(
    const int* __restrict__ rawpos, const float* __restrict__ control,
    const float* __restrict__ latent,
    const float* __restrict__ Wc, const float* __restrict__ bc,
    const float* __restrict__ Wt, const float* __restrict__ bt,
    const float* __restrict__ b1, const float* __restrict__ b2,
    const unsigned short* __restrict__ ws, float* __restrict__ out)
{
    __shared__ __align__(16) unsigned char smem[32768];
    const int tid = threadIdx.x;
    const int i = blockIdx.x * 256 + tid;
    const unsigned char* wsb = (const unsigned char*)ws;

    // ============ phase 1: per-point features -> LDS (pk-f32 math) ====
    {
        const int px = rawpos[2 * i], py = rawpos[2 * i + 1];
        const float c0 = control[2 * i], c1 = control[2 * i + 1];
        const float4 lat = *reinterpret_cast<const float4*>(latent + 4 * (py * IMGW + px));
        const int pxc = min(max(px, 0), IMGW - 1), pyc = min(max(py, 0), IMGH - 1);
        const float xf = (float)pxc * (1.0f / IMGW);
        const float yf = (float)pyc * (1.0f / IMGH);
        const float2 sxv = ((const float2*)(wsb + TS_OFF))[pxc];
        const float2 syv = ((const float2*)(wsb + TS_OFF))[pyc];

        unsigned char* myrow = &smem[tid * 128];
        const int sw = tid & 7;

        {   // control feat (2->16) -> groups 0,1
            const f32x2* Wc2 = (const f32x2*)Wc;
            const f32x2* bc2 = (const f32x2*)bc;
            const f32x2 c0s = mk2(c0, c0), c1s = mk2(c1, c1);
            f32x2 cf[8];
            #pragma unroll
            for (int jp = 0; jp < 8; ++jp) {
                f32x2 a = __builtin_elementwise_fma(c1s, Wc2[8 + jp], bc2[jp]);
                a = __builtin_elementwise_fma(c0s, Wc2[jp], a);
                cf[jp] = __builtin_elementwise_max(a, mk2(0.f, 0.f));
            }
            #pragma unroll
            for (int g = 0; g < 2; ++g) {
                u32x4 q = { pk2(cf[4*g+0].x, cf[4*g+0].y), pk2(cf[4*g+1].x, cf[4*g+1].y),
                            pk2(cf[4*g+2].x, cf[4*g+2].y), pk2(cf[4*g+3].x, cf[4*g+3].y) };
                *(u32x4*)(myrow + ((g ^ sw) << 4)) = q;
            }
        }
        {   // pos feat from tables -> groups 2,3
            const f32x4* tx = (const f32x4*)((const float*)(wsb + TX_OFF) + pxc * 16);
            const f32x4* ty = (const f32x4*)((const float*)(wsb + TY_OFF) + pyc * 16);
            const f32x4 z4 = {0.f, 0.f, 0.f, 0.f};
            #pragma unroll
            for (int g = 0; g < 2; ++g) {
                f32x4 u0 = __builtin_elementwise_max(tx[2*g]   + ty[2*g],   z4);
                f32x4 u1 = __builtin_elementwise_max(tx[2*g+1] + ty[2*g+1], z4);
                u32x4 q = { pk2(u0.x, u0.y), pk2(u0.z, u0.w), pk2(u1.x, u1.y), pk2(u1.z, u1.w) };
                *(u32x4*)(myrow + (((2 + g) ^ sw) << 4)) = q;
            }
        }
        {   // time feat (6->16) -> groups 4,5
            const float st[6] = { s2pi(c0), c2pi(c0), s2pi(2.f * c0), c2pi(2.f * c0), s2pi(3.f * c0), c2pi(3.f * c0) };
            const f32x2* Wt2 = (const f32x2*)Wt;
            const f32x2* bt2 = (const f32x2*)bt;
            f32x2 tf[8];
            #pragma unroll
            for (int jp = 0; jp < 8; ++jp) tf[jp] = bt2[jp];
            #pragma unroll
            for (int k = 0; k < 6; ++k) {
                const f32x2 s = mk2(st[k], st[k]);
                #pragma unroll
                for (int jp = 0; jp < 8; ++jp)
                    tf[jp] = __builtin_elementwise_fma(s, Wt2[k * 8 + jp], tf[jp]);
            }
            #pragma unroll
            for (int jp = 0; jp < 8; ++jp) tf[jp] = __builtin_elementwise_max(tf[jp], mk2(0.f, 0.f));
            #pragma unroll
            for (int g = 0; g < 2; ++g) {
                u32x4 q = { pk2(tf[4*g+0].x, tf[4*g+0].y), pk2(tf[4*g+1].x, tf[4*g+1].y),
                            pk2(tf[4*g+2].x, tf[4*g+2].y), pk2(tf[4*g+3].x, tf[4*g+3].y) };
                *(u32x4*)(myrow + (((4 + g) ^ sw) << 4)) = q;
            }
        }
        {   // main_in tail -> groups 6,7 (feature 58 = 1.0 -> bias row of WB)
            u32x4 q6 = { pk2(lat.x, lat.y), pk2(lat.z, lat.w),
                         pk2(xf, yf),       pk2(sxv.x, syv.x) };
            *(u32x4*)(myrow + ((6 ^ sw) << 4)) = q6;
            u32x4 q7 = { pk2(sxv.y, syv.y), pk2(1.0f, 0.f), 0u, 0u };
            *(u32x4*)(myrow + ((7 ^ sw) << 4)) = q7;
        }
    }
    CFENCE();   // same-wave DS in-order: no HW wait needed

    // ================= phase 2: MFMA pipeline (wave-private) =================
    const int lane = tid & 63, wv = tid >> 6;
    const int cl = lane & 15, lg = lane >> 4;
    const bf16x8* WBf = (const bf16x8*)ws;

    float biasW1[4];
    #pragma unroll
    for (int n = 0; n < 4; ++n) biasW1[n] = b1[n * 16 + cl];
    const float biasO = (cl < 4) ? b2[cl] : 0.f;

    const f32x4 z4 = {0.f, 0.f, 0.f, 0.f};
    unsigned char* wbase = &smem[(wv * 64) * 128];   // this wave's 8 KB region

    // ---- preload ALL A fragments; featL region then dead -> hT aliases it.
    // (Stores into the aliased region are issued later in program order; the
    // in-order DS pipe guarantees these reads complete first.)
    bf16x8 A0[4], A1[4];
    #pragma unroll
    for (int mt = 0; mt < 4; ++mt) {
        const int rowA = wv * 64 + mt * 16 + cl;
        A0[mt] = *(const bf16x8*)(&smem[rowA * 128 + (((0 + lg) ^ (rowA & 7)) << 4)]);
        A1[mt] = *(const bf16x8*)(&smem[rowA * 128 + (((4 + lg) ^ (rowA & 7)) << 4)]);
    }
    CFENCE();

    // ---- hoist GEMM2/GEMM3 B fragments (loaded ONCE per wave) ----
    bf16x8 W1f[8];
    #pragma unroll
    for (int q = 0; q < 8; ++q) W1f[q] = WBf[1536 + q * 64 + lane];
    const bf16x8 W2f0 = WBf[2048 + lane];
    const bf16x8 W2f1 = WBf[2048 + 64 + lane];

    // ---- GEMM1: n-outer (6 B-frags loaded once per n), mt-inner ----
    #pragma unroll 1
    for (int n = 0; n < 4; ++n) {
        const bf16x8 bg0 = WBf[(n * 2 + 0) * 64 + lane];
        const bf16x8 bg1 = WBf[(n * 2 + 1) * 64 + lane];
        const bf16x8 bb0 = WBf[((4 + n) * 2 + 0) * 64 + lane];
        const bf16x8 bb1 = WBf[((4 + n) * 2 + 1) * 64 + lane];
        const bf16x8 bh0 = WBf[((8 + n) * 2 + 0) * 64 + lane];
        const bf16x8 bh1 = WBf[((8 + n) * 2 + 1) * 64 + lane];
        #pragma unroll
        for (int mt = 0; mt < 4; ++mt) {
            f32x4 cg = MFMA(A0[mt], bg0, z4); cg = MFMA(A1[mt], bg1, cg);
            f32x4 cb = MFMA(A0[mt], bb0, z4); cb = MFMA(A1[mt], bb1, cb);
            f32x4 ch = MFMA(A0[mt], bh0, z4); ch = MFMA(A1[mt], bh1, ch);
            f32x2 x01 = __builtin_elementwise_fma(mk2(cg[0], cg[1]), mk2(ch[0], ch[1]), mk2(cb[0], cb[1]));
            f32x2 x23 = __builtin_elementwise_fma(mk2(cg[2], cg[3]), mk2(ch[2], ch[3]), mk2(cb[2], cb[3]));
            f32x2 q01 = gelu2(x01), q23 = gelu2(x23);
            const float hv[4] = { q01.x, q01.y, q23.x, q23.y };
            unsigned char* hTm = wbase + mt * 2048;
            #pragma unroll
            for (int r = 0; r < 4; ++r) {
                const int row = lg * 4 + r, col = n * 16 + cl;
                *(unsigned short*)(&hTm[row * 128 + (((col >> 3) ^ (row & 7)) << 4) + (col & 7) * 2]) = f2bf(hv[r]);
            }
        }
    }
    CFENCE();

    // ---- GEMM2: all mt (reads follow GEMM1 stores in program order;
    // h2 overwrites h in place — reads of h(mt) are issued before the
    // stores of h2(mt), and the DS pipe is in-order). ----
    #pragma unroll 1
    for (int mt = 0; mt < 4; ++mt) {
        unsigned char* hTm = wbase + mt * 2048;
        bf16x8 h0f = *(const bf16x8*)(&hTm[cl * 128 + (((0 + lg) ^ (cl & 7)) << 4)]);
        bf16x8 h1f = *(const bf16x8*)(&hTm[cl * 128 + (((4 + lg) ^ (cl & 7)) << 4)]);
        #pragma unroll
        for (int n = 0; n < 4; ++n) {
            f32x4 c = { biasW1[n], biasW1[n], biasW1[n], biasW1[n] };
            c = MFMA(h0f, W1f[n * 2 + 0], c);
            c = MFMA(h1f, W1f[n * 2 + 1], c);
            f32x2 q01 = gelu2(mk2(c[0], c[1])), q23 = gelu2(mk2(c[2], c[3]));
            const float hv[4] = { q01.x, q01.y, q23.x, q23.y };
            #pragma unroll
            for (int r = 0; r < 4; ++r) {
                const int row = lg * 4 + r, col = n * 16 + cl;
                *(unsigned short*)(&hTm[row * 128 + (((col >> 3) ^ (row & 7)) << 4) + (col & 7) * 2]) = f2bf(hv[r]);
            }
        }
    }
    CFENCE();

    // ---- GEMM3: all mt ----
    #pragma unroll 1
    for (int mt = 0; mt < 4; ++mt) {
        unsigned char* hTm = wbase + mt * 2048;
        bf16x8 g0f = *(const bf16x8*)(&hTm[cl * 128 + (((0 + lg) ^ (cl & 7)) << 4)]);
        bf16x8 g1f = *(const bf16x8*)(&hTm[cl * 128 + (((4 + lg) ^ (cl & 7)) << 4)]);
        f32x4 c3 = { biasO, biasO, biasO, biasO };
        c3 = MFMA(g0f, W2f0, c3);
        c3 = MFMA(g1f, W2f1, c3);

        if (cl < 4) {
            const int pb = blockIdx.x * 256 + wv * 64 + mt * 16 + lg * 4;
            #pragma unroll
            for (int r = 0; r < 4; ++r) {
                const float e = __builtin_amdgcn_exp2f(c3[r] * -1.44269504f);
                out[(pb + r) * 4 + cl] = __builtin_amdgcn_rcpf(1.f + e);
            }
        }
    }
}

extern "C" void kernel_launch(void* const* d_in, const int* in_sizes, int n_in,
                              void* d_out, int out_size, void* d_ws, size_t ws_size,
                              hipStream_t stream) {
    const int*   rawpos  = (const int*)  d_in[0];
    const float* control = (const float*)d_in[1];
    const float* latent  = (const float*)d_in[2];
    const float* Wc = (const float*)d_in[3];
    const float* bc = (const float*)d_in[4];
    const float* Wt = (const float*)d_in[5];
    const float* bt = (const float*)d_in[6];
    const float* Wp = (const float*)d_in[7];
    const float* bp = (const float*)d_in[8];
    const float* Wf = (const float*)d_in[9];
    const float* bf = (const float*)d_in[10];
    const float* W0 = (const float*)d_in[11];
    const float* b0 = (const float*)d_in[12];
    const float* W1 = (const float*)d_in[13];
    const float* b1 = (const float*)d_in[14];
    const float* W2 = (const float*)d_in[15];
    const float* b2 = (const float*)d_in[16];

    unsigned short* ws = (unsigned short*)d_ws;
    prepack<<<(PREP_ITEMS + 255) / 256, 256, 0, stream>>>(Wf, W0, W1, W2, Wp, bp, bf, b0, ws);
    vfx_fwd<<<NPTS / 256, 256, 0, stream>>>(rawpos, control, latent,
                                            Wc, bc, Wt, bt,
                                            b1, b2, ws, (float*)d_out);
}

// Round 9
// 185.370 us; speedup vs baseline: 1.0050x; 1.0050x over previous
//
#include <hip/hip_runtime.h>
#include <hip/hip_bf16.h>
#include <math.h>

#define NPTS 2097152
#define IMGW 1024
#define IMGH 1024

typedef __attribute__((ext_vector_type(8))) short bf16x8;   // 8 bf16 = 4 VGPR
typedef __attribute__((ext_vector_type(4))) float f32x4;
typedef __attribute__((ext_vector_type(2))) float f32x2;
typedef __attribute__((ext_vector_type(2))) unsigned int u32x2;
typedef __attribute__((ext_vector_type(4))) unsigned int u32x4;

// ws layout (bytes):
//   [0,      34816)  weight frags (17408 ushorts):
//       [0, 12288)     WB: fused [Wf(48xk) ; W0(10xk) ; bias row 58] -> K=64, N=192.
//                      12 ntiles x 2 ksteps x 64 lanes x 8 bf16 fragments.
//                      ntile 0..3 = gamma, 4..7 = beta, 8..11 = h0 cols.
//                      Row 58 holds bff/b0 (feature 58 == 1.0 in phase 1).
//       [12288,16384)  W1: 4 ntiles x 2 ksteps x 64 x 8
//       [16384,17408)  W2: 1 ntile  x 2 ksteps x 64 x 8  (cols 4..15 zero)
//   [34816, 100352)  tX: f32[1024][16]  = Wp_x @ spiral_x(px)          (64 KB)
//   [100352,165888)  tY: f32[1024][16]  = Wp_y @ spiral_y(py) + bp     (64 KB)
//   [165888,174080)  tS: float2[1024]   = {sin(2pi p/1024), sin(4pi p/1024)}
// Requires ws_size >= 174080 bytes.
#define TX_OFF 34816
#define TY_OFF 100352
#define TS_OFF 165888
#define PREP_ITEMS 51200   // 17408 + 16384 + 16384 + 1024

__device__ __forceinline__ unsigned short f2bf(float f) {
    __hip_bfloat16 h = __float2bfloat16(f);          // RTNE; pairs fuse to v_cvt_pk_bf16_f32
    return __builtin_bit_cast(unsigned short, h);
}
__device__ __forceinline__ unsigned pk2(float a, float b) {
    return (unsigned)f2bf(a) | ((unsigned)f2bf(b) << 16);
}
__device__ __forceinline__ f32x2 mk2(float a, float b) { f32x2 r; r.x = a; r.y = b; return r; }

__device__ __forceinline__ float s2pi(float r) { r = r - floorf(r); return __builtin_amdgcn_sinf(r); }
__device__ __forceinline__ float c2pi(float r) { r = r + 0.25f; r = r - floorf(r); return __builtin_amdgcn_sinf(r); }

__global__ __launch_bounds__(256) void prepack(
    const float* __restrict__ Wf, const float* __restrict__ W0,
    const float* __restrict__ W1, const float* __restrict__ W2,
    const float* __restrict__ Wp, const float* __restrict__ bp,
    const float* __restrict__ bff, const float* __restrict__ b0,
    unsigned short* __restrict__ ws)
{
    int idx = blockIdx.x * 256 + threadIdx.x;
    if (idx < 17408) {                           // ---- weight fragments ----
        float val = 0.f;
        if (idx < 12288) {                       // fused Wf|W0 -> B frags (K=64)
            int e = idx, i = e & 7, l = (e >> 3) & 63, ks = (e >> 9) & 1, n = e >> 10;
            int k = ks * 32 + (l >> 4) * 8 + i;
            int c16 = l & 15;
            if (n < 8) {
                if (k < 48) val = Wf[k * 128 + n * 16 + c16];
                else if (k == 58) val = bff[n * 16 + c16];           // bias row
            } else {
                if (k >= 48 && k < 58) val = W0[(k - 48) * 64 + (n - 8) * 16 + c16];
                else if (k == 58) val = b0[(n - 8) * 16 + c16];      // bias row
            }
        } else if (idx < 16384) {                // W1 (64x64)
            int e = idx - 12288, i = e & 7, l = (e >> 3) & 63, ks = (e >> 9) & 1, n = e >> 10;
            int k = ks * 32 + (l >> 4) * 8 + i;
            val = W1[k * 64 + n * 16 + (l & 15)];
        } else {                                 // W2 (64x4, N padded to 16)
            int e = idx - 16384, i = e & 7, l = (e >> 3) & 63, ks = (e >> 9) & 1;
            int k = ks * 32 + (l >> 4) * 8 + i;
            int c = l & 15;
            if (c < 4) val = W2[k * 4 + c];
        }
        ws[idx] = f2bf(val);
    } else if (idx < 33792) {                    // ---- tX ----
        int e = idx - 17408, p = e >> 4, j = e & 15;
        float xf = (float)p * (1.0f / IMGW);
        float s[6] = { s2pi(xf), c2pi(xf), s2pi(2.f * xf), c2pi(2.f * xf), s2pi(3.f * xf), c2pi(3.f * xf) };
        float a = 0.f;
        #pragma unroll
        for (int k = 0; k < 6; ++k) a = fmaf(s[k], Wp[k * 16 + j], a);
        ((float*)((char*)ws + TX_OFF))[p * 16 + j] = a;
    } else if (idx < 50176) {                    // ---- tY (bias folded) ----
        int e = idx - 33792, p = e >> 4, j = e & 15;
        float yf = (float)p * (1.0f / IMGH);
        float s[6] = { s2pi(yf), c2pi(yf), s2pi(2.f * yf), c2pi(2.f * yf), s2pi(3.f * yf), c2pi(3.f * yf) };
        float a = bp[j];
        #pragma unroll
        for (int k = 0; k < 6; ++k) a = fmaf(s[k], Wp[(6 + k) * 16 + j], a);
        ((float*)((char*)ws + TY_OFF))[p * 16 + j] = a;
    } else if (idx < 51200) {                    // ---- tS ----
        int p = idx - 50176;
        float xf = (float)p * (1.0f / IMGW);
        float2 v; v.x = s2pi(xf); v.y = s2pi(2.f * xf);
        ((float2*)((char*)ws + TS_OFF))[p] = v;
    }
}

// Exact-GELU (A&S 7.1.25 erf, |gelu err| < 1e-5) — R4/R6/R7's proven version.
// (R8's inline-asm v_pk_* variant failed correctness — VOP3P default-modifier
// semantics unverifiable here; permanently parked.)
__device__ __forceinline__ f32x2 gelu2(f32x2 x) {
    const f32x2 ax = __builtin_elementwise_abs(x);
    f32x2 den = __builtin_elementwise_fma(ax, mk2(0.33269077f, 0.33269077f), mk2(1.0f, 1.0f));
    f32x2 t; t.x = __builtin_amdgcn_rcpf(den.x); t.y = __builtin_amdgcn_rcpf(den.y);
    f32x2 p = __builtin_elementwise_fma(t, mk2(0.37392780f, 0.37392780f), mk2(-0.04793990f, -0.04793990f));
    p = __builtin_elementwise_fma(t, p, mk2(0.17401210f, 0.17401210f));
    p = p * t;
    f32x2 w = (ax * ax) * mk2(-0.72134752f, -0.72134752f);
    f32x2 e; e.x = __builtin_amdgcn_exp2f(w.x); e.y = __builtin_amdgcn_exp2f(w.y);
    f32x2 r = __builtin_elementwise_max(x, mk2(0.f, 0.f));
    return __builtin_elementwise_fma(-ax, p * e, r);
}

#define MFMA(a, b, c) __builtin_amdgcn_mfma_f32_16x16x32_bf16((a), (b), (c), 0, 0, 0)

// Compiler-only reorder fence (R7: wave-private LDS + in-order DS pipe ->
// no hardware lgkmcnt drains needed; compiler auto-inserts data-dep waits).
#define CFENCE() asm volatile("" ::: "memory")

// R9 structural change — TRANSPOSED MFMA (pure operand swap, exact algebra):
// For mfma_16x16x32_bf16 the A-fragment lane map (row=l&15, k=(l>>4)*8+i) and
// B-fragment lane map (col=l&15, k=(l>>4)*8+i) are the SAME function — both
// independently harness-proven in this kernel (feat reads prove A, prepacked
// WB proves B). Swapping operands (W as A, feat/h as B) therefore feeds each
// slot its proven layout and yields D^T: lane holds point=col=cl,
// hidden=row=lg*4+r. The 4 per-lane results become CONSECUTIVE hidden units:
//   - hT store: ONE ds_write_b64 per (n,mt) instead of 4x ds_write_b16
//     (DS writes/wave 128 -> 32); read side unchanged (proven b128 reads).
//   - GEMM2 bias: contiguous f32x4 load b1[n*16+lg*4..+3] as MFMA C operand.
//   - GEMM3 output: lane (lg==0, cl) holds all 4 channels of point cl ->
//     one global_store_dwordx4 per point (output stores 64 -> 16 per wave).
//
// LDS: featL = 256 rows x 64 bf16 (128 B/row, XOR-swizzled 16B granules) = 32 KB.
// hT tiles alias the wave's own featL rows (dead after the A-fragment preload).
// Wave-private everywhere -> NO __syncthreads.
__global__ __launch_bounds__(256) void vfx_fwd(
    const int* __restrict__ rawpos, const float* __restrict__ control,
    const float* __restrict__ latent,
    const float* __restrict__ Wc, const float* __restrict__ bc,
    const float* __restrict__ Wt, const float* __restrict__ bt,
    const float* __restrict__ b1, const float* __restrict__ b2,
    const unsigned short* __restrict__ ws, float* __restrict__ out)
{
    __shared__ __align__(16) unsigned char smem[32768];
    const int tid = threadIdx.x;
    const int i = blockIdx.x * 256 + tid;
    const unsigned char* wsb = (const unsigned char*)ws;

    // ============ phase 1: per-point features -> LDS (R7's proven code) ====
    {
        const int px = rawpos[2 * i], py = rawpos[2 * i + 1];
        const float c0 = control[2 * i], c1 = control[2 * i + 1];
        const float4 lat = *reinterpret_cast<const float4*>(latent + 4 * (py * IMGW + px));
        const int pxc = min(max(px, 0), IMGW - 1), pyc = min(max(py, 0), IMGH - 1);
        const float xf = (float)pxc * (1.0f / IMGW);
        const float yf = (float)pyc * (1.0f / IMGH);
        const float2 sxv = ((const float2*)(wsb + TS_OFF))[pxc];
        const float2 syv = ((const float2*)(wsb + TS_OFF))[pyc];

        unsigned char* myrow = &smem[tid * 128];
        const int sw = tid & 7;

        {   // control feat (2->16) -> groups 0,1
            const f32x2* Wc2 = (const f32x2*)Wc;
            const f32x2* bc2 = (const f32x2*)bc;
            const f32x2 c0s = mk2(c0, c0), c1s = mk2(c1, c1);
            f32x2 cf[8];
            #pragma unroll
            for (int jp = 0; jp < 8; ++jp) {
                f32x2 a = __builtin_elementwise_fma(c1s, Wc2[8 + jp], bc2[jp]);
                a = __builtin_elementwise_fma(c0s, Wc2[jp], a);
                cf[jp] = __builtin_elementwise_max(a, mk2(0.f, 0.f));
            }
            #pragma unroll
            for (int g = 0; g < 2; ++g) {
                u32x4 q = { pk2(cf[4*g+0].x, cf[4*g+0].y), pk2(cf[4*g+1].x, cf[4*g+1].y),
                            pk2(cf[4*g+2].x, cf[4*g+2].y), pk2(cf[4*g+3].x, cf[4*g+3].y) };
                *(u32x4*)(myrow + ((g ^ sw) << 4)) = q;
            }
        }
        {   // pos feat from tables -> groups 2,3
            const f32x4* tx = (const f32x4*)((const float*)(wsb + TX_OFF) + pxc * 16);
            const f32x4* ty = (const f32x4*)((const float*)(wsb + TY_OFF) + pyc * 16);
            const f32x4 z4 = {0.f, 0.f, 0.f, 0.f};
            #pragma unroll
            for (int g = 0; g < 2; ++g) {
                f32x4 u0 = __builtin_elementwise_max(tx[2*g]   + ty[2*g],   z4);
                f32x4 u1 = __builtin_elementwise_max(tx[2*g+1] + ty[2*g+1], z4);
                u32x4 q = { pk2(u0.x, u0.y), pk2(u0.z, u0.w), pk2(u1.x, u1.y), pk2(u1.z, u1.w) };
                *(u32x4*)(myrow + (((2 + g) ^ sw) << 4)) = q;
            }
        }
        {   // time feat (6->16) -> groups 4,5
            const float st[6] = { s2pi(c0), c2pi(c0), s2pi(2.f * c0), c2pi(2.f * c0), s2pi(3.f * c0), c2pi(3.f * c0) };
            const f32x2* Wt2 = (const f32x2*)Wt;
            const f32x2* bt2 = (const f32x2*)bt;
            f32x2 tf[8];
            #pragma unroll
            for (int jp = 0; jp < 8; ++jp) tf[jp] = bt2[jp];
            #pragma unroll
            for (int k = 0; k < 6; ++k) {
                const f32x2 s = mk2(st[k], st[k]);
                #pragma unroll
                for (int jp = 0; jp < 8; ++jp)
                    tf[jp] = __builtin_elementwise_fma(s, Wt2[k * 8 + jp], tf[jp]);
            }
            #pragma unroll
            for (int jp = 0; jp < 8; ++jp) tf[jp] = __builtin_elementwise_max(tf[jp], mk2(0.f, 0.f));
            #pragma unroll
            for (int g = 0; g < 2; ++g) {
                u32x4 q = { pk2(tf[4*g+0].x, tf[4*g+0].y), pk2(tf[4*g+1].x, tf[4*g+1].y),
                            pk2(tf[4*g+2].x, tf[4*g+2].y), pk2(tf[4*g+3].x, tf[4*g+3].y) };
                *(u32x4*)(myrow + (((4 + g) ^ sw) << 4)) = q;
            }
        }
        {   // main_in tail -> groups 6,7 (feature 58 = 1.0 -> bias row of WB)
            u32x4 q6 = { pk2(lat.x, lat.y), pk2(lat.z, lat.w),
                         pk2(xf, yf),       pk2(sxv.x, syv.x) };
            *(u32x4*)(myrow + ((6 ^ sw) << 4)) = q6;
            u32x4 q7 = { pk2(sxv.y, syv.y), pk2(1.0f, 0.f), 0u, 0u };
            *(u32x4*)(myrow + ((7 ^ sw) << 4)) = q7;
        }
    }
    CFENCE();   // same-wave DS in-order: no HW wait needed

    // ================= phase 2: transposed-MFMA pipeline (wave-private) ======
    const int lane = tid & 63, wv = tid >> 6;
    const int cl = lane & 15, lg = lane >> 4;
    const bf16x8* WBf = (const bf16x8*)ws;

    const f32x4 z4 = {0.f, 0.f, 0.f, 0.f};
    unsigned char* wbase = &smem[(wv * 64) * 128];   // this wave's 8 KB region

    // GEMM2 bias as direct C operand: c[r] = b1[n*16 + lg*4 + r] (contig f32x4)
    f32x4 bW1v[4];
    #pragma unroll
    for (int n = 0; n < 4; ++n) bW1v[n] = *(const f32x4*)(b1 + n * 16 + lg * 4);
    // GEMM3 bias: channels live in rows lg*4+r; only lg==0 rows are real.
    f32x4 bOv = z4;
    if (lg == 0) bOv = *(const f32x4*)b2;

    // ---- preload ALL A fragments; featL region then dead -> hT aliases it ----
    bf16x8 A0[4], A1[4];
    #pragma unroll
    for (int mt = 0; mt < 4; ++mt) {
        const int rowA = wv * 64 + mt * 16 + cl;
        A0[mt] = *(const bf16x8*)(&smem[rowA * 128 + (((0 + lg) ^ (rowA & 7)) << 4)]);
        A1[mt] = *(const bf16x8*)(&smem[rowA * 128 + (((4 + lg) ^ (rowA & 7)) << 4)]);
    }
    CFENCE();

    // ---- hoist GEMM2/GEMM3 weight fragments (loaded ONCE per wave) ----
    bf16x8 W1f[8];
    #pragma unroll
    for (int q = 0; q < 8; ++q) W1f[q] = WBf[1536 + q * 64 + lane];
    const bf16x8 W2f0 = WBf[2048 + lane];
    const bf16x8 W2f1 = WBf[2048 + 64 + lane];

    // store base for transposed D: point=cl row, hidden byte (lg&1)*8 sub-slot
    const int wrb = cl * 128 + ((lg & 1) << 3);

    // ---- GEMM1: n-outer (6 B-frags loaded once per n), mt-inner; W as A ----
    #pragma unroll 1
    for (int n = 0; n < 4; ++n) {
        const bf16x8 bg0 = WBf[(n * 2 + 0) * 64 + lane];
        const bf16x8 bg1 = WBf[(n * 2 + 1) * 64 + lane];
        const bf16x8 bb0 = WBf[((4 + n) * 2 + 0) * 64 + lane];
        const bf16x8 bb1 = WBf[((4 + n) * 2 + 1) * 64 + lane];
        const bf16x8 bh0 = WBf[((8 + n) * 2 + 0) * 64 + lane];
        const bf16x8 bh1 = WBf[((8 + n) * 2 + 1) * 64 + lane];
        const int gsw = (((2 * n) + (lg >> 1)) ^ (cl & 7)) << 4;   // swizzled granule
        #pragma unroll
        for (int mt = 0; mt < 4; ++mt) {
            f32x4 cg = MFMA(bg0, A0[mt], z4); cg = MFMA(bg1, A1[mt], cg);
            f32x4 cb = MFMA(bb0, A0[mt], z4); cb = MFMA(bb1, A1[mt], cb);
            f32x4 ch = MFMA(bh0, A0[mt], z4); ch = MFMA(bh1, A1[mt], ch);
            f32x2 x01 = __builtin_elementwise_fma(mk2(cg[0], cg[1]), mk2(ch[0], ch[1]), mk2(cb[0], cb[1]));
            f32x2 x23 = __builtin_elementwise_fma(mk2(cg[2], cg[3]), mk2(ch[2], ch[3]), mk2(cb[2], cb[3]));
            f32x2 q01 = gelu2(x01), q23 = gelu2(x23);
            u32x2 d = { pk2(q01.x, q01.y), pk2(q23.x, q23.y) };   // hidden lg*4+0..3
            *(u32x2*)(&(wbase + mt * 2048)[wrb + gsw]) = d;       // one b64 store
        }
    }
    CFENCE();

    // ---- GEMM2: all mt; h as B operand (reads unchanged, proven layout) ----
    #pragma unroll 1
    for (int mt = 0; mt < 4; ++mt) {
        unsigned char* hTm = wbase + mt * 2048;
        bf16x8 h0f = *(const bf16x8*)(&hTm[cl * 128 + (((0 + lg) ^ (cl & 7)) << 4)]);
        bf16x8 h1f = *(const bf16x8*)(&hTm[cl * 128 + (((4 + lg) ^ (cl & 7)) << 4)]);
        #pragma unroll
        for (int n = 0; n < 4; ++n) {
            f32x4 c = MFMA(W1f[n * 2 + 0], h0f, bW1v[n]);
            c = MFMA(W1f[n * 2 + 1], h1f, c);
            f32x2 q01 = gelu2(mk2(c[0], c[1])), q23 = gelu2(mk2(c[2], c[3]));
            u32x2 d = { pk2(q01.x, q01.y), pk2(q23.x, q23.y) };
            const int gsw = (((2 * n) + (lg >> 1)) ^ (cl & 7)) << 4;
            *(u32x2*)(&hTm[wrb + gsw]) = d;
        }
    }
    CFENCE();

    // ---- GEMM3: all mt; D[channel][point] -> lg==0 lane stores 4 channels
    // of point cl as one dwordx4 ----
    const int pbase = blockIdx.x * 256 + wv * 64;
    #pragma unroll 1
    for (int mt = 0; mt < 4; ++mt) {
        unsigned char* hTm = wbase + mt * 2048;
        bf16x8 g0f = *(const bf16x8*)(&hTm[cl * 128 + (((0 + lg) ^ (cl & 7)) << 4)]);
        bf16x8 g1f = *(const bf16x8*)(&hTm[cl * 128 + (((4 + lg) ^ (cl & 7)) << 4)]);
        f32x4 c3 = MFMA(W2f0, g0f, bOv);
        c3 = MFMA(W2f1, g1f, c3);

        if (lg == 0) {
            f32x4 o;
            #pragma unroll
            for (int r = 0; r < 4; ++r) {
                const float e = __builtin_amdgcn_exp2f(c3[r] * -1.44269504f);
                o[r] = __builtin_amdgcn_rcpf(1.f + e);
            }
            *(f32x4*)(out + (pbase + mt * 16 + cl) * 4) = o;
        }
    }
}

extern "C" void kernel_launch(void* const* d_in, const int* in_sizes, int n_in,
                              void* d_out, int out_size, void* d_ws, size_t ws_size,
                              hipStream_t stream) {
    const int*   rawpos  = (const int*)  d_in[0];
    const float* control = (const float*)d_in[1];
    const float* latent  = (const float*)d_in[2];
    const float* Wc = (const float*)d_in[3];
    const float* bc = (const float*)d_in[4];
    const float* Wt = (const float*)d_in[5];
    const float* bt = (const float*)d_in[6];
    const float* Wp = (const float*)d_in[7];
    const float* bp = (const float*)d_in[8];
    const float* Wf = (const float*)d_in[9];
    const float* bf = (const float*)d_in[10];
    const float* W0 = (const float*)d_in[11];
    const float* b0 = (const float*)d_in[12];
    const float* W1 = (const float*)d_in[13];
    const float* b1 = (const float*)d_in[14];
    const float* W2 = (const float*)d_in[15];
    const float* b2 = (const float*)d_in[16];

    unsigned short* ws = (unsigned short*)d_ws;
    prepack<<<(PREP_ITEMS + 255) / 256, 256, 0, stream>>>(Wf, W0, W1, W2, Wp, bp, bf, b0, ws);
    vfx_fwd<<<NPTS / 256, 256, 0, stream>>>(rawpos, control, latent,
                                            Wc, bc, Wt, bt,
                                            b1, b2, ws, (float*)d_out);
}

// Round 10
// 158.811 us; speedup vs baseline: 1.1730x; 1.1672x over previous
//
#include <hip/hip_runtime.h>
#include <hip/hip_bf16.h>
#include <math.h>

#define NPTS 2097152
#define IMGW 1024
#define IMGH 1024

typedef __attribute__((ext_vector_type(8))) short bf16x8;   // 8 bf16 = 4 VGPR
typedef __attribute__((ext_vector_type(4))) float f32x4;
typedef __attribute__((ext_vector_type(2))) float f32x2;
typedef __attribute__((ext_vector_type(2))) unsigned int u32x2;
typedef __attribute__((ext_vector_type(4))) unsigned int u32x4;

// ws layout (bytes):
//   [0,      34816)  weight frags (17408 ushorts):
//       [0, 12288)     WB: fused [Wf(48xk) ; W0(10xk) ; bias row 58] -> K=64, N=192.
//                      12 ntiles x 2 ksteps x 64 lanes x 8 bf16 fragments.
//                      ntile 0..3 = gamma, 4..7 = beta, 8..11 = h0 cols.
//                      Row 58 holds bff/b0 (feature 58 == 1.0 in phase 1).
//       [12288,16384)  W1: 4 ntiles x 2 ksteps x 64 x 8
//       [16384,17408)  W2: 1 ntile  x 2 ksteps x 64 x 8  (cols 4..15 zero)
//   [34816, 100352)  tX: f32[1024][16]  = Wp_x @ spiral_x(px)          (64 KB)
//   [100352,165888)  tY: f32[1024][16]  = Wp_y @ spiral_y(py) + bp     (64 KB)
//   [165888,174080)  tS: float2[1024]   = {sin(2pi p/1024), sin(4pi p/1024)}
// Requires ws_size >= 174080 bytes.
#define TX_OFF 34816
#define TY_OFF 100352
#define TS_OFF 165888
#define PREP_ITEMS 51200   // 17408 + 16384 + 16384 + 1024

__device__ __forceinline__ unsigned short f2bf(float f) {
    __hip_bfloat16 h = __float2bfloat16(f);          // RTNE; pairs fuse to v_cvt_pk_bf16_f32
    return __builtin_bit_cast(unsigned short, h);
}
__device__ __forceinline__ unsigned pk2(float a, float b) {
    return (unsigned)f2bf(a) | ((unsigned)f2bf(b) << 16);
}
__device__ __forceinline__ f32x2 mk2(float a, float b) { f32x2 r; r.x = a; r.y = b; return r; }

__device__ __forceinline__ float s2pi(float r) { r = r - floorf(r); return __builtin_amdgcn_sinf(r); }
__device__ __forceinline__ float c2pi(float r) { r = r + 0.25f; r = r - floorf(r); return __builtin_amdgcn_sinf(r); }

__global__ __launch_bounds__(256) void prepack(
    const float* __restrict__ Wf, const float* __restrict__ W0,
    const float* __restrict__ W1, const float* __restrict__ W2,
    const float* __restrict__ Wp, const float* __restrict__ bp,
    const float* __restrict__ bff, const float* __restrict__ b0,
    unsigned short* __restrict__ ws)
{
    int idx = blockIdx.x * 256 + threadIdx.x;
    if (idx < 17408) {                           // ---- weight fragments ----
        float val = 0.f;
        if (idx < 12288) {                       // fused Wf|W0 -> B frags (K=64)
            int e = idx, i = e & 7, l = (e >> 3) & 63, ks = (e >> 9) & 1, n = e >> 10;
            int k = ks * 32 + (l >> 4) * 8 + i;
            int c16 = l & 15;
            if (n < 8) {
                if (k < 48) val = Wf[k * 128 + n * 16 + c16];
                else if (k == 58) val = bff[n * 16 + c16];           // bias row
            } else {
                if (k >= 48 && k < 58) val = W0[(k - 48) * 64 + (n - 8) * 16 + c16];
                else if (k == 58) val = b0[(n - 8) * 16 + c16];      // bias row
            }
        } else if (idx < 16384) {                // W1 (64x64)
            int e = idx - 12288, i = e & 7, l = (e >> 3) & 63, ks = (e >> 9) & 1, n = e >> 10;
            int k = ks * 32 + (l >> 4) * 8 + i;
            val = W1[k * 64 + n * 16 + (l & 15)];
        } else {                                 // W2 (64x4, N padded to 16)
            int e = idx - 16384, i = e & 7, l = (e >> 3) & 63, ks = (e >> 9) & 1;
            int k = ks * 32 + (l >> 4) * 8 + i;
            int c = l & 15;
            if (c < 4) val = W2[k * 4 + c];
        }
        ws[idx] = f2bf(val);
    } else if (idx < 33792) {                    // ---- tX ----
        int e = idx - 17408, p = e >> 4, j = e & 15;
        float xf = (float)p * (1.0f / IMGW);
        float s[6] = { s2pi(xf), c2pi(xf), s2pi(2.f * xf), c2pi(2.f * xf), s2pi(3.f * xf), c2pi(3.f * xf) };
        float a = 0.f;
        #pragma unroll
        for (int k = 0; k < 6; ++k) a = fmaf(s[k], Wp[k * 16 + j], a);
        ((float*)((char*)ws + TX_OFF))[p * 16 + j] = a;
    } else if (idx < 50176) {                    // ---- tY (bias folded) ----
        int e = idx - 33792, p = e >> 4, j = e & 15;
        float yf = (float)p * (1.0f / IMGH);
        float s[6] = { s2pi(yf), c2pi(yf), s2pi(2.f * yf), c2pi(2.f * yf), s2pi(3.f * yf), c2pi(3.f * yf) };
        float a = bp[j];
        #pragma unroll
        for (int k = 0; k < 6; ++k) a = fmaf(s[k], Wp[(6 + k) * 16 + j], a);
        ((float*)((char*)ws + TY_OFF))[p * 16 + j] = a;
    } else if (idx < 51200) {                    // ---- tS ----
        int p = idx - 50176;
        float xf = (float)p * (1.0f / IMGW);
        float2 v; v.x = s2pi(xf); v.y = s2pi(2.f * xf);
        ((float2*)((char*)ws + TS_OFF))[p] = v;
    }
}

// R10: tanh-form GELU — gelu(x) = x * sigmoid(2*sqrt(2/pi)*(x + 0.044715 x^3)),
// folded to 5 VALU + 2 TRANS per element (vs 9+2 for the A&S erf form):
//   x2 = x*x;  m = fma(x2, -K2, -K);  e = exp2(x*m);  s = rcp(1+e);  out = x*s
// with K = 2*sqrt(2/pi)*log2(e) = 2.30220818, K2 = K*0.044715 = 0.10294324
// (log2 fold exact). Limits: x->-inf => e->inf => s->0 => 0; x->+inf => e->0
// => s->1 => x. Max deviation from exact erf-GELU <= ~4e-4 (x=1:1.1e-4,
// x=2:2.7e-4, x=3:3.8e-4) — an order below the bf16 h-storage error (4e-3);
// test threshold is 1.41e-2.
__device__ __forceinline__ f32x2 gelu2(f32x2 x) {
    const f32x2 x2 = x * x;
    f32x2 m = __builtin_elementwise_fma(x2, mk2(-0.10294324f, -0.10294324f),
                                        mk2(-2.30220818f, -2.30220818f));
    f32x2 a = x * m;
    f32x2 e; e.x = __builtin_amdgcn_exp2f(a.x); e.y = __builtin_amdgcn_exp2f(a.y);
    f32x2 s; s.x = __builtin_amdgcn_rcpf(1.f + e.x); s.y = __builtin_amdgcn_rcpf(1.f + e.y);
    return x * s;
}

#define MFMA(a, b, c) __builtin_amdgcn_mfma_f32_16x16x32_bf16((a), (b), (c), 0, 0, 0)

// Compiler-only reorder fence (R7: wave-private LDS + in-order DS pipe ->
// no hardware lgkmcnt drains needed; compiler auto-inserts data-dep waits).
#define CFENCE() asm volatile("" ::: "memory")

// TRANSPOSED MFMA structure (R9, harness-proven): W as A-operand, feat/h as
// B-operand -> D^T: lane holds point=cl, hidden=lg*4+r. One ds_write_b64 per
// (n,mt); GEMM3 stores one dwordx4 per point from lg==0 lanes.
// LDS: featL = 256 rows x 64 bf16 (XOR-swizzled 16B granules) = 32 KB; hT
// tiles alias the wave's own featL rows (dead after A-fragment preload).
// Wave-private everywhere -> NO __syncthreads.
__global__ __launch_bounds__(256) void vfx_fwd(
    const int* __restrict__ rawpos, const float* __restrict__ control,
    const float* __restrict__ latent,
    const float* __restrict__ Wc, const float* __restrict__ bc,
    const float* __restrict__ Wt, const float* __restrict__ bt,
    const float* __restrict__ b1, const float* __restrict__ b2,
    const unsigned short* __restrict__ ws, float* __restrict__ out)
{
    __shared__ __align__(16) unsigned char smem[32768];
    const int tid = threadIdx.x;
    const int i = blockIdx.x * 256 + tid;
    const unsigned char* wsb = (const unsigned char*)ws;

    // ============ phase 1: per-point features -> LDS (proven code) ====
    {
        const int px = rawpos[2 * i], py = rawpos[2 * i + 1];
        const float c0 = control[2 * i], c1 = control[2 * i + 1];
        const float4 lat = *reinterpret_cast<const float4*>(latent + 4 * (py * IMGW + px));
        const int pxc = min(max(px, 0), IMGW - 1), pyc = min(max(py, 0), IMGH - 1);
        const float xf = (float)pxc * (1.0f / IMGW);
        const float yf = (float)pyc * (1.0f / IMGH);
        const float2 sxv = ((const float2*)(wsb + TS_OFF))[pxc];
        const float2 syv = ((const float2*)(wsb + TS_OFF))[pyc];

        unsigned char* myrow = &smem[tid * 128];
        const int sw = tid & 7;

        {   // control feat (2->16) -> groups 0,1
            const f32x2* Wc2 = (const f32x2*)Wc;
            const f32x2* bc2 = (const f32x2*)bc;
            const f32x2 c0s = mk2(c0, c0), c1s = mk2(c1, c1);
            f32x2 cf[8];
            #pragma unroll
            for (int jp = 0; jp < 8; ++jp) {
                f32x2 a = __builtin_elementwise_fma(c1s, Wc2[8 + jp], bc2[jp]);
                a = __builtin_elementwise_fma(c0s, Wc2[jp], a);
                cf[jp] = __builtin_elementwise_max(a, mk2(0.f, 0.f));
            }
            #pragma unroll
            for (int g = 0; g < 2; ++g) {
                u32x4 q = { pk2(cf[4*g+0].x, cf[4*g+0].y), pk2(cf[4*g+1].x, cf[4*g+1].y),
                            pk2(cf[4*g+2].x, cf[4*g+2].y), pk2(cf[4*g+3].x, cf[4*g+3].y) };
                *(u32x4*)(myrow + ((g ^ sw) << 4)) = q;
            }
        }
        {   // pos feat from tables -> groups 2,3
            const f32x4* tx = (const f32x4*)((const float*)(wsb + TX_OFF) + pxc * 16);
            const f32x4* ty = (const f32x4*)((const float*)(wsb + TY_OFF) + pyc * 16);
            const f32x4 z4 = {0.f, 0.f, 0.f, 0.f};
            #pragma unroll
            for (int g = 0; g < 2; ++g) {
                f32x4 u0 = __builtin_elementwise_max(tx[2*g]   + ty[2*g],   z4);
                f32x4 u1 = __builtin_elementwise_max(tx[2*g+1] + ty[2*g+1], z4);
                u32x4 q = { pk2(u0.x, u0.y), pk2(u0.z, u0.w), pk2(u1.x, u1.y), pk2(u1.z, u1.w) };
                *(u32x4*)(myrow + (((2 + g) ^ sw) << 4)) = q;
            }
        }
        {   // time feat (6->16) -> groups 4,5
            const float st[6] = { s2pi(c0), c2pi(c0), s2pi(2.f * c0), c2pi(2.f * c0), s2pi(3.f * c0), c2pi(3.f * c0) };
            const f32x2* Wt2 = (const f32x2*)Wt;
            const f32x2* bt2 = (const f32x2*)bt;
            f32x2 tf[8];
            #pragma unroll
            for (int jp = 0; jp < 8; ++jp) tf[jp] = bt2[jp];
            #pragma unroll
            for (int k = 0; k < 6; ++k) {
                const f32x2 s = mk2(st[k], st[k]);
                #pragma unroll
                for (int jp = 0; jp < 8; ++jp)
                    tf[jp] = __builtin_elementwise_fma(s, Wt2[k * 8 + jp], tf[jp]);
            }
            #pragma unroll
            for (int jp = 0; jp < 8; ++jp) tf[jp] = __builtin_elementwise_max(tf[jp], mk2(0.f, 0.f));
            #pragma unroll
            for (int g = 0; g < 2; ++g) {
                u32x4 q = { pk2(tf[4*g+0].x, tf[4*g+0].y), pk2(tf[4*g+1].x, tf[4*g+1].y),
                            pk2(tf[4*g+2].x, tf[4*g+2].y), pk2(tf[4*g+3].x, tf[4*g+3].y) };
                *(u32x4*)(myrow + (((4 + g) ^ sw) << 4)) = q;
            }
        }
        {   // main_in tail -> groups 6,7 (feature 58 = 1.0 -> bias row of WB)
            u32x4 q6 = { pk2(lat.x, lat.y), pk2(lat.z, lat.w),
                         pk2(xf, yf),       pk2(sxv.x, syv.x) };
            *(u32x4*)(myrow + ((6 ^ sw) << 4)) = q6;
            u32x4 q7 = { pk2(sxv.y, syv.y), pk2(1.0f, 0.f), 0u, 0u };
            *(u32x4*)(myrow + ((7 ^ sw) << 4)) = q7;
        }
    }
    CFENCE();   // same-wave DS in-order: no HW wait needed

    // ================= phase 2: transposed-MFMA pipeline (wave-private) ======
    const int lane = tid & 63, wv = tid >> 6;
    const int cl = lane & 15, lg = lane >> 4;
    const bf16x8* WBf = (const bf16x8*)ws;

    const f32x4 z4 = {0.f, 0.f, 0.f, 0.f};
    unsigned char* wbase = &smem[(wv * 64) * 128];   // this wave's 8 KB region

    // GEMM2 bias as direct C operand: c[r] = b1[n*16 + lg*4 + r] (contig f32x4)
    f32x4 bW1v[4];
    #pragma unroll
    for (int n = 0; n < 4; ++n) bW1v[n] = *(const f32x4*)(b1 + n * 16 + lg * 4);
    // GEMM3 bias: channels live in rows lg*4+r; only lg==0 rows are real.
    f32x4 bOv = z4;
    if (lg == 0) bOv = *(const f32x4*)b2;

    // ---- preload ALL A fragments; featL region then dead -> hT aliases it ----
    bf16x8 A0[4], A1[4];
    #pragma unroll
    for (int mt = 0; mt < 4; ++mt) {
        const int rowA = wv * 64 + mt * 16 + cl;
        A0[mt] = *(const bf16x8*)(&smem[rowA * 128 + (((0 + lg) ^ (rowA & 7)) << 4)]);
        A1[mt] = *(const bf16x8*)(&smem[rowA * 128 + (((4 + lg) ^ (rowA & 7)) << 4)]);
    }
    CFENCE();

    // ---- hoist GEMM2/GEMM3 weight fragments (loaded ONCE per wave) ----
    bf16x8 W1f[8];
    #pragma unroll
    for (int q = 0; q < 8; ++q) W1f[q] = WBf[1536 + q * 64 + lane];
    const bf16x8 W2f0 = WBf[2048 + lane];
    const bf16x8 W2f1 = WBf[2048 + 64 + lane];

    // store base for transposed D: point=cl row, hidden byte (lg&1)*8 sub-slot
    const int wrb = cl * 128 + ((lg & 1) << 3);

    // ---- GEMM1: n-outer (6 B-frags loaded once per n), mt-inner; W as A ----
    #pragma unroll 1
    for (int n = 0; n < 4; ++n) {
        const bf16x8 bg0 = WBf[(n * 2 + 0) * 64 + lane];
        const bf16x8 bg1 = WBf[(n * 2 + 1) * 64 + lane];
        const bf16x8 bb0 = WBf[((4 + n) * 2 + 0) * 64 + lane];
        const bf16x8 bb1 = WBf[((4 + n) * 2 + 1) * 64 + lane];
        const bf16x8 bh0 = WBf[((8 + n) * 2 + 0) * 64 + lane];
        const bf16x8 bh1 = WBf[((8 + n) * 2 + 1) * 64 + lane];
        const int gsw = (((2 * n) + (lg >> 1)) ^ (cl & 7)) << 4;   // swizzled granule
        #pragma unroll
        for (int mt = 0; mt < 4; ++mt) {
            f32x4 cg = MFMA(bg0, A0[mt], z4); cg = MFMA(bg1, A1[mt], cg);
            f32x4 cb = MFMA(bb0, A0[mt], z4); cb = MFMA(bb1, A1[mt], cb);
            f32x4 ch = MFMA(bh0, A0[mt], z4); ch = MFMA(bh1, A1[mt], ch);
            f32x2 x01 = __builtin_elementwise_fma(mk2(cg[0], cg[1]), mk2(ch[0], ch[1]), mk2(cb[0], cb[1]));
            f32x2 x23 = __builtin_elementwise_fma(mk2(cg[2], cg[3]), mk2(ch[2], ch[3]), mk2(cb[2], cb[3]));
            f32x2 q01 = gelu2(x01), q23 = gelu2(x23);
            u32x2 d = { pk2(q01.x, q01.y), pk2(q23.x, q23.y) };   // hidden lg*4+0..3
            *(u32x2*)(&(wbase + mt * 2048)[wrb + gsw]) = d;       // one b64 store
        }
    }
    CFENCE();

    // ---- GEMM2: all mt; h as B operand (reads unchanged, proven layout) ----
    #pragma unroll 1
    for (int mt = 0; mt < 4; ++mt) {
        unsigned char* hTm = wbase + mt * 2048;
        bf16x8 h0f = *(const bf16x8*)(&hTm[cl * 128 + (((0 + lg) ^ (cl & 7)) << 4)]);
        bf16x8 h1f = *(const bf16x8*)(&hTm[cl * 128 + (((4 + lg) ^ (cl & 7)) << 4)]);
        #pragma unroll
        for (int n = 0; n < 4; ++n) {
            f32x4 c = MFMA(W1f[n * 2 + 0], h0f, bW1v[n]);
            c = MFMA(W1f[n * 2 + 1], h1f, c);
            f32x2 q01 = gelu2(mk2(c[0], c[1])), q23 = gelu2(mk2(c[2], c[3]));
            u32x2 d = { pk2(q01.x, q01.y), pk2(q23.x, q23.y) };
            const int gsw = (((2 * n) + (lg >> 1)) ^ (cl & 7)) << 4;
            *(u32x2*)(&hTm[wrb + gsw]) = d;
        }
    }
    CFENCE();

    // ---- GEMM3: all mt; D[channel][point] -> lg==0 lane stores 4 channels
    // of point cl as one dwordx4 ----
    const int pbase = blockIdx.x * 256 + wv * 64;
    #pragma unroll 1
    for (int mt = 0; mt < 4; ++mt) {
        unsigned char* hTm = wbase + mt * 2048;
        bf16x8 g0f = *(const bf16x8*)(&hTm[cl * 128 + (((0 + lg) ^ (cl & 7)) << 4)]);
        bf16x8 g1f = *(const bf16x8*)(&hTm[cl * 128 + (((4 + lg) ^ (cl & 7)) << 4)]);
        f32x4 c3 = MFMA(W2f0, g0f, bOv);
        c3 = MFMA(W2f1, g1f, c3);

        if (lg == 0) {
            f32x4 o;
            #pragma unroll
            for (int r = 0; r < 4; ++r) {
                const float e = __builtin_amdgcn_exp2f(c3[r] * -1.44269504f);
                o[r] = __builtin_amdgcn_rcpf(1.f + e);
            }
            *(f32x4*)(out + (pbase + mt * 16 + cl) * 4) = o;
        }
    }
}

extern "C" void kernel_launch(void* const* d_in, const int* in_sizes, int n_in,
                              void* d_out, int out_size, void* d_ws, size_t ws_size,
                              hipStream_t stream) {
    const int*   rawpos  = (const int*)  d_in[0];
    const float* control = (const float*)d_in[1];
    const float* latent  = (const float*)d_in[2];
    const float* Wc = (const float*)d_in[3];
    const float* bc = (const float*)d_in[4];
    const float* Wt = (const float*)d_in[5];
    const float* bt = (const float*)d_in[6];
    const float* Wp = (const float*)d_in[7];
    const float* bp = (const float*)d_in[8];
    const float* Wf = (const float*)d_in[9];
    const float* bf = (const float*)d_in[10];
    const float* W0 = (const float*)d_in[11];
    const float* b0 = (const float*)d_in[12];
    const float* W1 = (const float*)d_in[13];
    const float* b1 = (const float*)d_in[14];
    const float* W2 = (const float*)d_in[15];
    const float* b2 = (const float*)d_in[16];

    unsigned short* ws = (unsigned short*)d_ws;
    prepack<<<(PREP_ITEMS + 255) / 256, 256, 0, stream>>>(Wf, W0, W1, W2, Wp, bp, bf, b0, ws);
    vfx_fwd<<<NPTS / 256, 256, 0, stream>>>(rawpos, control, latent,
                                            Wc, bc, Wt, bt,
                                            b1, b2, ws, (float*)d_out);
}

// Round 11
// 141.958 us; speedup vs baseline: 1.3123x; 1.1187x over previous
//
#include <hip/hip_runtime.h>
#include <hip/hip_bf16.h>
#include <math.h>

#define NPTS 2097152
#define IMGW 1024
#define IMGH 1024

typedef __attribute__((ext_vector_type(8))) short bf16x8;   // 8 bf16 = 4 VGPR
typedef __attribute__((ext_vector_type(4))) float f32x4;
typedef __attribute__((ext_vector_type(2))) float f32x2;
typedef __attribute__((ext_vector_type(2))) unsigned int u32x2;
typedef __attribute__((ext_vector_type(4))) unsigned int u32x4;

// ws layout (bytes):
//   [0,      34816)  weight frags (17408 ushorts):
//       [0, 12288)     WB: fused [Wf(48xk) ; W0(10xk) ; bias row 58] -> K=64, N=192.
//                      12 ntiles x 2 ksteps x 64 lanes x 8 bf16 fragments.
//                      ntile 0..3 = gamma, 4..7 = beta, 8..11 = h0 cols.
//                      Row 58 holds bff/b0 (feature 58 == 1.0 in phase 1).
//       [12288,16384)  W1: 4 ntiles x 2 ksteps x 64 x 8
//       [16384,17408)  W2: 1 ntile  x 2 ksteps x 64 x 8  (cols 4..15 zero)
//   [34816, 100352)  tX: f32[1024][16]  = Wp_x @ spiral_x(px)          (64 KB)
//   [100352,165888)  tY: f32[1024][16]  = Wp_y @ spiral_y(py) + bp     (64 KB)
//   [165888,174080)  tS: float2[1024]   = {sin(2pi p/1024), sin(4pi p/1024)}
// Requires ws_size >= 174080 bytes.
#define TX_OFF 34816
#define TY_OFF 100352
#define TS_OFF 165888
#define PREP_ITEMS 51200   // 17408 + 16384 + 16384 + 1024

__device__ __forceinline__ unsigned short f2bf(float f) {
    __hip_bfloat16 h = __float2bfloat16(f);          // RTNE; pairs fuse to v_cvt_pk_bf16_f32
    return __builtin_bit_cast(unsigned short, h);
}
__device__ __forceinline__ unsigned pk2(float a, float b) {
    return (unsigned)f2bf(a) | ((unsigned)f2bf(b) << 16);
}
__device__ __forceinline__ f32x2 mk2(float a, float b) { f32x2 r; r.x = a; r.y = b; return r; }

__device__ __forceinline__ float s2pi(float r) { r = r - floorf(r); return __builtin_amdgcn_sinf(r); }
__device__ __forceinline__ float c2pi(float r) { r = r + 0.25f; r = r - floorf(r); return __builtin_amdgcn_sinf(r); }

__global__ __launch_bounds__(256) void prepack(
    const float* __restrict__ Wf, const float* __restrict__ W0,
    const float* __restrict__ W1, const float* __restrict__ W2,
    const float* __restrict__ Wp, const float* __restrict__ bp,
    const float* __restrict__ bff, const float* __restrict__ b0,
    unsigned short* __restrict__ ws)
{
    int idx = blockIdx.x * 256 + threadIdx.x;
    if (idx < 17408) {                           // ---- weight fragments ----
        float val = 0.f;
        if (idx < 12288) {                       // fused Wf|W0 -> B frags (K=64)
            int e = idx, i = e & 7, l = (e >> 3) & 63, ks = (e >> 9) & 1, n = e >> 10;
            int k = ks * 32 + (l >> 4) * 8 + i;
            int c16 = l & 15;
            if (n < 8) {
                if (k < 48) val = Wf[k * 128 + n * 16 + c16];
                else if (k == 58) val = bff[n * 16 + c16];           // bias row
            } else {
                if (k >= 48 && k < 58) val = W0[(k - 48) * 64 + (n - 8) * 16 + c16];
                else if (k == 58) val = b0[(n - 8) * 16 + c16];      // bias row
            }
        } else if (idx < 16384) {                // W1 (64x64)
            int e = idx - 12288, i = e & 7, l = (e >> 3) & 63, ks = (e >> 9) & 1, n = e >> 10;
            int k = ks * 32 + (l >> 4) * 8 + i;
            val = W1[k * 64 + n * 16 + (l & 15)];
        } else {                                 // W2 (64x4, N padded to 16)
            int e = idx - 16384, i = e & 7, l = (e >> 3) & 63, ks = (e >> 9) & 1;
            int k = ks * 32 + (l >> 4) * 8 + i;
            int c = l & 15;
            if (c < 4) val = W2[k * 4 + c];
        }
        ws[idx] = f2bf(val);
    } else if (idx < 33792) {                    // ---- tX ----
        int e = idx - 17408, p = e >> 4, j = e & 15;
        float xf = (float)p * (1.0f / IMGW);
        float s[6] = { s2pi(xf), c2pi(xf), s2pi(2.f * xf), c2pi(2.f * xf), s2pi(3.f * xf), c2pi(3.f * xf) };
        float a = 0.f;
        #pragma unroll
        for (int k = 0; k < 6; ++k) a = fmaf(s[k], Wp[k * 16 + j], a);
        ((float*)((char*)ws + TX_OFF))[p * 16 + j] = a;
    } else if (idx < 50176) {                    // ---- tY (bias folded) ----
        int e = idx - 33792, p = e >> 4, j = e & 15;
        float yf = (float)p * (1.0f / IMGH);
        float s[6] = { s2pi(yf), c2pi(yf), s2pi(2.f * yf), c2pi(2.f * yf), s2pi(3.f * yf), c2pi(3.f * yf) };
        float a = bp[j];
        #pragma unroll
        for (int k = 0; k < 6; ++k) a = fmaf(s[k], Wp[(6 + k) * 16 + j], a);
        ((float*)((char*)ws + TY_OFF))[p * 16 + j] = a;
    } else if (idx < 51200) {                    // ---- tS ----
        int p = idx - 50176;
        float xf = (float)p * (1.0f / IMGW);
        float2 v; v.x = s2pi(xf); v.y = s2pi(2.f * xf);
        ((float2*)((char*)ws + TS_OFF))[p] = v;
    }
}

// R10's tanh-form GELU (harness-proven): 5 VALU + 2 TRANS per element.
//   x2 = x*x;  m = fma(x2, -K2, -K);  e = exp2(x*m);  s = rcp(1+e);  out = x*s
// K = 2*sqrt(2/pi)*log2(e) = 2.30220818, K2 = K*0.044715 = 0.10294324.
// Max deviation from exact erf-GELU ~4e-4, well under the 1.41e-2 threshold.
__device__ __forceinline__ f32x2 gelu2(f32x2 x) {
    const f32x2 x2 = x * x;
    f32x2 m = __builtin_elementwise_fma(x2, mk2(-0.10294324f, -0.10294324f),
                                        mk2(-2.30220818f, -2.30220818f));
    f32x2 a = x * m;
    f32x2 e; e.x = __builtin_amdgcn_exp2f(a.x); e.y = __builtin_amdgcn_exp2f(a.y);
    f32x2 s; s.x = __builtin_amdgcn_rcpf(1.f + e.x); s.y = __builtin_amdgcn_rcpf(1.f + e.y);
    return x * s;
}

#define MFMA(a, b, c) __builtin_amdgcn_mfma_f32_16x16x32_bf16((a), (b), (c), 0, 0, 0)

// Compiler-only reorder fence (R7: wave-private LDS + in-order DS pipe ->
// no hardware lgkmcnt drains needed; compiler auto-inserts data-dep waits).
#define CFENCE() asm volatile("" ::: "memory")

// TRANSPOSED MFMA structure (R9, harness-proven): W as A-operand, feat/h as
// B-operand -> D^T: lane holds point=cl, hidden=lg*4+r. One ds_write_b64 per
// (n,mt); GEMM3 stores one dwordx4 per point from lg==0 lanes.
// LDS: featL = 256 rows x 64 bf16 (XOR-swizzled 16B granules) = 32 KB; hT
// tiles alias the wave's own featL rows (dead after A-fragment preload).
// Wave-private everywhere -> NO __syncthreads.
//
// R11 — occupancy probe: achieved occupancy has been pinned at ~55% of the
// static LDS/VGPR limits across R2/R6/R10 (29.6% = ~2.4 waves/SIMD at
// reported VGPR=80). Hypothesis: reported VGPR is arch-only; unified-file acc
// allocation pushes true usage to ~160-170/wave, capping residency at ~3
// waves/SIMD. Force 4 waves/SIMD with __launch_bounds__(256,4) (<=128 total
// regs) and slim the live set to fit: KEEP A0/A1 + W1f hoists (the proven
// L2-dedup wins), move cold GEMM3 weights + small bias vectors to in-loop
// loads (L1-resident, rematerializable). Spill tripwire: WRITE_SIZE must stay
// exactly 32768 KB (R1 signature check).
__global__ __launch_bounds__(256, 4) void vfx_fwd(
    const int* __restrict__ rawpos, const float* __restrict__ control,
    const float* __restrict__ latent,
    const float* __restrict__ Wc, const float* __restrict__ bc,
    const float* __restrict__ Wt, const float* __restrict__ bt,
    const float* __restrict__ b1, const float* __restrict__ b2,
    const unsigned short* __restrict__ ws, float* __restrict__ out)
{
    __shared__ __align__(16) unsigned char smem[32768];
    const int tid = threadIdx.x;
    const int i = blockIdx.x * 256 + tid;
    const unsigned char* wsb = (const unsigned char*)ws;

    // ============ phase 1: per-point features -> LDS (proven code) ====
    {
        const int px = rawpos[2 * i], py = rawpos[2 * i + 1];
        const float c0 = control[2 * i], c1 = control[2 * i + 1];
        const float4 lat = *reinterpret_cast<const float4*>(latent + 4 * (py * IMGW + px));
        const int pxc = min(max(px, 0), IMGW - 1), pyc = min(max(py, 0), IMGH - 1);
        const float xf = (float)pxc * (1.0f / IMGW);
        const float yf = (float)pyc * (1.0f / IMGH);
        const float2 sxv = ((const float2*)(wsb + TS_OFF))[pxc];
        const float2 syv = ((const float2*)(wsb + TS_OFF))[pyc];

        unsigned char* myrow = &smem[tid * 128];
        const int sw = tid & 7;

        {   // control feat (2->16) -> groups 0,1
            const f32x2* Wc2 = (const f32x2*)Wc;
            const f32x2* bc2 = (const f32x2*)bc;
            const f32x2 c0s = mk2(c0, c0), c1s = mk2(c1, c1);
            f32x2 cf[8];
            #pragma unroll
            for (int jp = 0; jp < 8; ++jp) {
                f32x2 a = __builtin_elementwise_fma(c1s, Wc2[8 + jp], bc2[jp]);
                a = __builtin_elementwise_fma(c0s, Wc2[jp], a);
                cf[jp] = __builtin_elementwise_max(a, mk2(0.f, 0.f));
            }
            #pragma unroll
            for (int g = 0; g < 2; ++g) {
                u32x4 q = { pk2(cf[4*g+0].x, cf[4*g+0].y), pk2(cf[4*g+1].x, cf[4*g+1].y),
                            pk2(cf[4*g+2].x, cf[4*g+2].y), pk2(cf[4*g+3].x, cf[4*g+3].y) };
                *(u32x4*)(myrow + ((g ^ sw) << 4)) = q;
            }
        }
        {   // pos feat from tables -> groups 2,3
            const f32x4* tx = (const f32x4*)((const float*)(wsb + TX_OFF) + pxc * 16);
            const f32x4* ty = (const f32x4*)((const float*)(wsb + TY_OFF) + pyc * 16);
            const f32x4 z4 = {0.f, 0.f, 0.f, 0.f};
            #pragma unroll
            for (int g = 0; g < 2; ++g) {
                f32x4 u0 = __builtin_elementwise_max(tx[2*g]   + ty[2*g],   z4);
                f32x4 u1 = __builtin_elementwise_max(tx[2*g+1] + ty[2*g+1], z4);
                u32x4 q = { pk2(u0.x, u0.y), pk2(u0.z, u0.w), pk2(u1.x, u1.y), pk2(u1.z, u1.w) };
                *(u32x4*)(myrow + (((2 + g) ^ sw) << 4)) = q;
            }
        }
        {   // time feat (6->16) -> groups 4,5
            const float st[6] = { s2pi(c0), c2pi(c0), s2pi(2.f * c0), c2pi(2.f * c0), s2pi(3.f * c0), c2pi(3.f * c0) };
            const f32x2* Wt2 = (const f32x2*)Wt;
            const f32x2* bt2 = (const f32x2*)bt;
            f32x2 tf[8];
            #pragma unroll
            for (int jp = 0; jp < 8; ++jp) tf[jp] = bt2[jp];
            #pragma unroll
            for (int k = 0; k < 6; ++k) {
                const f32x2 s = mk2(st[k], st[k]);
                #pragma unroll
                for (int jp = 0; jp < 8; ++jp)
                    tf[jp] = __builtin_elementwise_fma(s, Wt2[k * 8 + jp], tf[jp]);
            }
            #pragma unroll
            for (int jp = 0; jp < 8; ++jp) tf[jp] = __builtin_elementwise_max(tf[jp], mk2(0.f, 0.f));
            #pragma unroll
            for (int g = 0; g < 2; ++g) {
                u32x4 q = { pk2(tf[4*g+0].x, tf[4*g+0].y), pk2(tf[4*g+1].x, tf[4*g+1].y),
                            pk2(tf[4*g+2].x, tf[4*g+2].y), pk2(tf[4*g+3].x, tf[4*g+3].y) };
                *(u32x4*)(myrow + (((4 + g) ^ sw) << 4)) = q;
            }
        }
        {   // main_in tail -> groups 6,7 (feature 58 = 1.0 -> bias row of WB)
            u32x4 q6 = { pk2(lat.x, lat.y), pk2(lat.z, lat.w),
                         pk2(xf, yf),       pk2(sxv.x, syv.x) };
            *(u32x4*)(myrow + ((6 ^ sw) << 4)) = q6;
            u32x4 q7 = { pk2(sxv.y, syv.y), pk2(1.0f, 0.f), 0u, 0u };
            *(u32x4*)(myrow + ((7 ^ sw) << 4)) = q7;
        }
    }
    CFENCE();   // same-wave DS in-order: no HW wait needed

    // ================= phase 2: transposed-MFMA pipeline (wave-private) ======
    const int lane = tid & 63, wv = tid >> 6;
    const int cl = lane & 15, lg = lane >> 4;
    const bf16x8* WBf = (const bf16x8*)ws;

    const f32x4 z4 = {0.f, 0.f, 0.f, 0.f};
    unsigned char* wbase = &smem[(wv * 64) * 128];   // this wave's 8 KB region

    // ---- preload ALL A fragments; featL region then dead -> hT aliases it ----
    bf16x8 A0[4], A1[4];
    #pragma unroll
    for (int mt = 0; mt < 4; ++mt) {
        const int rowA = wv * 64 + mt * 16 + cl;
        A0[mt] = *(const bf16x8*)(&smem[rowA * 128 + (((0 + lg) ^ (rowA & 7)) << 4)]);
        A1[mt] = *(const bf16x8*)(&smem[rowA * 128 + (((4 + lg) ^ (rowA & 7)) << 4)]);
    }
    CFENCE();

    // ---- hoist GEMM2 weight fragments (reused 4x each; GEMM3 weights and
    // bias vectors are loaded in-loop to fit the 128-reg budget) ----
    bf16x8 W1f[8];
    #pragma unroll
    for (int q = 0; q < 8; ++q) W1f[q] = WBf[1536 + q * 64 + lane];

    // store base for transposed D: point=cl row, hidden byte (lg&1)*8 sub-slot
    const int wrb = cl * 128 + ((lg & 1) << 3);

    // ---- GEMM1: n-outer (6 B-frags loaded once per n), mt-inner; W as A ----
    #pragma unroll 1
    for (int n = 0; n < 4; ++n) {
        const bf16x8 bg0 = WBf[(n * 2 + 0) * 64 + lane];
        const bf16x8 bg1 = WBf[(n * 2 + 1) * 64 + lane];
        const bf16x8 bb0 = WBf[((4 + n) * 2 + 0) * 64 + lane];
        const bf16x8 bb1 = WBf[((4 + n) * 2 + 1) * 64 + lane];
        const bf16x8 bh0 = WBf[((8 + n) * 2 + 0) * 64 + lane];
        const bf16x8 bh1 = WBf[((8 + n) * 2 + 1) * 64 + lane];
        const int gsw = (((2 * n) + (lg >> 1)) ^ (cl & 7)) << 4;   // swizzled granule
        #pragma unroll
        for (int mt = 0; mt < 4; ++mt) {
            f32x4 cg = MFMA(bg0, A0[mt], z4); cg = MFMA(bg1, A1[mt], cg);
            f32x4 cb = MFMA(bb0, A0[mt], z4); cb = MFMA(bb1, A1[mt], cb);
            f32x4 ch = MFMA(bh0, A0[mt], z4); ch = MFMA(bh1, A1[mt], ch);
            f32x2 x01 = __builtin_elementwise_fma(mk2(cg[0], cg[1]), mk2(ch[0], ch[1]), mk2(cb[0], cb[1]));
            f32x2 x23 = __builtin_elementwise_fma(mk2(cg[2], cg[3]), mk2(ch[2], ch[3]), mk2(cb[2], cb[3]));
            f32x2 q01 = gelu2(x01), q23 = gelu2(x23);
            u32x2 d = { pk2(q01.x, q01.y), pk2(q23.x, q23.y) };   // hidden lg*4+0..3
            *(u32x2*)(&(wbase + mt * 2048)[wrb + gsw]) = d;       // one b64 store
        }
    }
    CFENCE();

    // ---- GEMM2: all mt; h as B operand (reads unchanged, proven layout).
    // bias loaded per (mt,n) from b1 (256 B, L1-resident, rematerializable) ----
    #pragma unroll 1
    for (int mt = 0; mt < 4; ++mt) {
        unsigned char* hTm = wbase + mt * 2048;
        bf16x8 h0f = *(const bf16x8*)(&hTm[cl * 128 + (((0 + lg) ^ (cl & 7)) << 4)]);
        bf16x8 h1f = *(const bf16x8*)(&hTm[cl * 128 + (((4 + lg) ^ (cl & 7)) << 4)]);
        #pragma unroll
        for (int n = 0; n < 4; ++n) {
            const f32x4 bw1 = *(const f32x4*)(b1 + n * 16 + lg * 4);
            f32x4 c = MFMA(W1f[n * 2 + 0], h0f, bw1);
            c = MFMA(W1f[n * 2 + 1], h1f, c);
            f32x2 q01 = gelu2(mk2(c[0], c[1])), q23 = gelu2(mk2(c[2], c[3]));
            u32x2 d = { pk2(q01.x, q01.y), pk2(q23.x, q23.y) };
            const int gsw = (((2 * n) + (lg >> 1)) ^ (cl & 7)) << 4;
            *(u32x2*)(&hTm[wrb + gsw]) = d;
        }
    }
    CFENCE();

    // ---- GEMM3: all mt; weights + bias loaded in-loop (cold, 1 KB, L2/L1).
    // D[channel][point] -> lg==0 lane stores 4 channels of point cl ----
    const int pbase = blockIdx.x * 256 + wv * 64;
    #pragma unroll 1
    for (int mt = 0; mt < 4; ++mt) {
        unsigned char* hTm = wbase + mt * 2048;
        bf16x8 g0f = *(const bf16x8*)(&hTm[cl * 128 + (((0 + lg) ^ (cl & 7)) << 4)]);
        bf16x8 g1f = *(const bf16x8*)(&hTm[cl * 128 + (((4 + lg) ^ (cl & 7)) << 4)]);
        const bf16x8 w2a = WBf[2048 + lane];
        const bf16x8 w2b = WBf[2048 + 64 + lane];
        f32x4 bOv = z4;
        if (lg == 0) bOv = *(const f32x4*)b2;
        f32x4 c3 = MFMA(w2a, g0f, bOv);
        c3 = MFMA(w2b, g1f, c3);

        if (lg == 0) {
            f32x4 o;
            #pragma unroll
            for (int r = 0; r < 4; ++r) {
                const float e = __builtin_amdgcn_exp2f(c3[r] * -1.44269504f);
                o[r] = __builtin_amdgcn_rcpf(1.f + e);
            }
            *(f32x4*)(out + (pbase + mt * 16 + cl) * 4) = o;
        }
    }
}

extern "C" void kernel_launch(void* const* d_in, const int* in_sizes, int n_in,
                              void* d_out, int out_size, void* d_ws, size_t ws_size,
                              hipStream_t stream) {
    const int*   rawpos  = (const int*)  d_in[0];
    const float* control = (const float*)d_in[1];
    const float* latent  = (const float*)d_in[2];
    const float* Wc = (const float*)d_in[3];
    const float* bc = (const float*)d_in[4];
    const float* Wt = (const float*)d_in[5];
    const float* bt = (const float*)d_in[6];
    const float* Wp = (const float*)d_in[7];
    const float* bp = (const float*)d_in[8];
    const float* Wf = (const float*)d_in[9];
    const float* bf = (const float*)d_in[10];
    const float* W0 = (const float*)d_in[11];
    const float* b0 = (const float*)d_in[12];
    const float* W1 = (const float*)d_in[13];
    const float* b1 = (const float*)d_in[14];
    const float* W2 = (const float*)d_in[15];
    const float* b2 = (const float*)d_in[16];

    unsigned short* ws = (unsigned short*)d_ws;
    prepack<<<(PREP_ITEMS + 255) / 256, 256, 0, stream>>>(Wf, W0, W1, W2, Wp, bp, bf, b0, ws);
    vfx_fwd<<<NPTS / 256, 256, 0, stream>>>(rawpos, control, latent,
                                            Wc, bc, Wt, bt,
                                            b1, b2, ws, (float*)d_out);
}